// Round 4
// baseline (1904.948 us; speedup 1.0000x reference)
//
#include <hip/hip_runtime.h>
#include <hip/hip_bf16.h>
#include <cstdint>
#include <cstddef>

#define DIM 192
#define NSL 11
#define NB 64
#define NN 4096
#define HIDN 128
#define NCH 8          // chunks per batch in k_iter (512 rows each)
#define LN_EPS 1e-5f
#define EPS_A 1e-8f
#define SCALE_Q 0.07216878364870323f  // 192^-0.5

// ---------------------------------------------------------------- utilities
__device__ __forceinline__ float wred(float v) {
#pragma unroll
  for (int m = 32; m; m >>= 1) v += __shfl_xor(v, m, 64);
  return v;
}

// ---------------------------------------------------------------- slots init
__global__ void k_init_slots(const float* __restrict__ noise, const float* __restrict__ mu,
                             const float* __restrict__ sig, float* __restrict__ slots) {
  int i = blockIdx.x * 256 + threadIdx.x;
  if (i < NB * NSL * DIM) {
    int d = i % DIM;
    slots[i] = mu[d] + sig[d] * noise[i];
  }
}

// ---------------------------------------------------------------- per-iter prep: LN(slots) -> q -> folded query
// qt[k][e] = SCALE * ln_in_w[e] * (q[k] @ Wk^T)[e];  t0[k] = sum_e qt;  cp[k] = SCALE*(q.bk + sum_e ln_in_b[e]*qk[k][e])
__global__ __launch_bounds__(192) void k_prep(
    const float* __restrict__ slots, const float* __restrict__ lnw, const float* __restrict__ lnb,
    const float* __restrict__ Wq, const float* __restrict__ bq,
    const float* __restrict__ Wk, const float* __restrict__ bk,
    const float* __restrict__ xw, const float* __restrict__ xb,
    float* __restrict__ qt, float* __restrict__ t0g, float* __restrict__ cpg) {
  const int b = blockIdx.x, tid = threadIdx.x, wave = tid >> 6, lane = tid & 63;
  __shared__ __align__(16) float sn[NSL][DIM];
  __shared__ __align__(16) float qb[NSL][DIM];
  __shared__ float red[3][NSL][2];

  for (int k = wave; k < NSL; k += 3) {
    const float* rp = slots + (size_t)(b * NSL + k) * DIM;
    float a = rp[lane], c = rp[lane + 64], e = rp[lane + 128];
    float s = wred(a + c + e), ss = wred(a * a + c * c + e * e);
    float mu = s * (1.0f / DIM), var = ss * (1.0f / DIM) - mu * mu;
    float rstd = rsqrtf(var + LN_EPS);
    sn[k][lane]       = (a - mu) * rstd * lnw[lane]       + lnb[lane];
    sn[k][lane + 64]  = (c - mu) * rstd * lnw[lane + 64]  + lnb[lane + 64];
    sn[k][lane + 128] = (e - mu) * rstd * lnw[lane + 128] + lnb[lane + 128];
  }
  __syncthreads();

  const int j = tid;
  float acc[NSL];
  const float bj = bq[j];
#pragma unroll
  for (int k = 0; k < NSL; ++k) acc[k] = bj;
  for (int d = 0; d < DIM; d += 4) {
    float w0 = Wq[(d + 0) * DIM + j], w1 = Wq[(d + 1) * DIM + j];
    float w2 = Wq[(d + 2) * DIM + j], w3 = Wq[(d + 3) * DIM + j];
#pragma unroll
    for (int k = 0; k < NSL; ++k) {
      float4 s4 = *(const float4*)&sn[k][d];
      acc[k] = fmaf(s4.w, w3, fmaf(s4.z, w2, fmaf(s4.y, w1, fmaf(s4.x, w0, acc[k]))));
    }
  }
#pragma unroll
  for (int k = 0; k < NSL; ++k) qb[k][j] = acc[k];
  __syncthreads();

  float qk[NSL];
#pragma unroll
  for (int k = 0; k < NSL; ++k) qk[k] = 0.f;
  const float* wkr = Wk + (size_t)j * DIM;
  for (int d = 0; d < DIM; d += 4) {
    float4 w4 = *(const float4*)(wkr + d);
#pragma unroll
    for (int k = 0; k < NSL; ++k) {
      float4 q4 = *(const float4*)&qb[k][d];
      qk[k] = fmaf(w4.w, q4.w, fmaf(w4.z, q4.z, fmaf(w4.y, q4.y, fmaf(w4.x, q4.x, qk[k]))));
    }
  }
  const float wj = xw[j], bxj = xb[j], bkj = bk[j];
#pragma unroll
  for (int k = 0; k < NSL; ++k) {
    float qtv = SCALE_Q * wj * qk[k];
    qt[((size_t)b * NSL + k) * DIM + j] = qtv;
    float r1 = wred(qtv);
    float r2 = wred(SCALE_Q * (bxj * qk[k] + qb[k][j] * bkj));
    if (lane == 0) { red[wave][k][0] = r1; red[wave][k][1] = r2; }
  }
  __syncthreads();
  if (tid < NSL) {
    t0g[b * NSL + tid] = red[0][tid][0] + red[1][tid][0] + red[2][tid][0];
    cpg[b * NSL + tid] = red[0][tid][1] + red[1][tid][1] + red[2][tid][1];
  }
}

// ---------------------------------------------------------------- fused: stats + dots + softmax + attn write + P1 partials
// grid (64, 8) x 256 threads. Block handles 512 rows = 8 tiles of 64.
// Thread t owns row t>>2, quarter t&3 of each tile (matches its own global loads).
__global__ __launch_bounds__(256) void k_iter(
    const float* __restrict__ x, const float* __restrict__ qt,
    const float* __restrict__ t0g, const float* __restrict__ cpg,
    float* __restrict__ attn_out, float* __restrict__ P1p,
    float* __restrict__ S_p, float* __restrict__ m1_p) {
  __shared__ float xs[64][196];              // +4 pad: odd float4 stride (49)
  __shared__ float qs[NSL][DIM];
  __shared__ float t0s[NSL], cps[NSL];
  __shared__ __align__(16) float a_lds[64][12];
  __shared__ float rs_lds[64];
  __shared__ float redS[4][NSL], redM[4][NSL];

  const int b = blockIdx.x, ch = blockIdx.y, tid = threadIdx.x;
  const int lane = tid & 63, wave = tid >> 6;
  const int r_own = tid >> 2, q = tid & 3;

  for (int t = tid; t < NSL * DIM; t += 256) qs[t / DIM][t % DIM] = qt[(size_t)b * NSL * DIM + t];
  if (tid < NSL) { t0s[tid] = t0g[b * NSL + tid]; cps[tid] = cpg[b * NSL + tid]; }

  const float* xbase = x + ((size_t)b * NN + ch * 512) * DIM;
  float4 xv[12];
  {
    const float4* g = (const float4*)xbase + tid * 12;
#pragma unroll
    for (int i = 0; i < 12; ++i) xv[i] = g[i];
  }

  float acc[NSL], sS[NSL], sM[NSL];
#pragma unroll
  for (int k = 0; k < NSL; ++k) { acc[k] = 0.f; sS[k] = 0.f; sM[k] = 0.f; }

  for (int T = 0; T < 8; ++T) {
    __syncthreads();                         // xs/a_lds free (prev tile consumed)
#pragma unroll
    for (int i = 0; i < 12; ++i)
      *(float4*)&xs[r_own][q * 48 + 4 * i] = xv[i];

    // dots + LN stats from registers
    float dot[NSL]; float s = 0.f, ss = 0.f;
#pragma unroll
    for (int k = 0; k < NSL; ++k) dot[k] = 0.f;
#pragma unroll
    for (int i = 0; i < 12; ++i) {
      float4 v = xv[i];
      s += (v.x + v.y) + (v.z + v.w);
      ss = fmaf(v.x, v.x, fmaf(v.y, v.y, fmaf(v.z, v.z, fmaf(v.w, v.w, ss))));
#pragma unroll
      for (int k = 0; k < NSL; ++k) {
        float4 qv = *(const float4*)&qs[k][q * 48 + 4 * i];
        dot[k] = fmaf(v.w, qv.w, fmaf(v.z, qv.z, fmaf(v.y, qv.y, fmaf(v.x, qv.x, dot[k]))));
      }
    }
    // prefetch next tile (latency hidden by softmax + phase C)
    if (T < 7) {
      const float4* g = (const float4*)(xbase + (size_t)(T + 1) * 64 * DIM) + tid * 12;
#pragma unroll
      for (int i = 0; i < 12; ++i) xv[i] = g[i];
    }
    // reduce quarters (lanes t, t^1, t^2 share a row)
#pragma unroll
    for (int k = 0; k < NSL; ++k) {
      dot[k] += __shfl_xor(dot[k], 1, 64);
      dot[k] += __shfl_xor(dot[k], 2, 64);
    }
    s += __shfl_xor(s, 1, 64);  s += __shfl_xor(s, 2, 64);
    ss += __shfl_xor(ss, 1, 64); ss += __shfl_xor(ss, 2, 64);

    if (q == 0) {
      float mu = s * (1.0f / DIM);
      float var = ss * (1.0f / DIM) - mu * mu;
      float rstd = rsqrtf(var + LN_EPS);
      float murstd = mu * rstd;
      float dv[NSL];
#pragma unroll
      for (int k = 0; k < NSL; ++k) dv[k] = fmaf(rstd, dot[k], fmaf(-murstd, t0s[k], cps[k]));
      float mx = dv[0];
#pragma unroll
      for (int k = 1; k < NSL; ++k) mx = fmaxf(mx, dv[k]);
      float es[NSL], sum = 0.f;
#pragma unroll
      for (int k = 0; k < NSL; ++k) { es[k] = __expf(dv[k] - mx); sum += es[k]; }
      float inv = 1.0f / sum;
#pragma unroll
      for (int k = 0; k < NSL; ++k) {
        float a = fmaf(es[k], inv, EPS_A);
        a_lds[r_own][k] = a;
        sS[k] += a;
        sM[k] = fmaf(a, murstd, sM[k]);
      }
      rs_lds[r_own] = rstd;
    }
    __syncthreads();                         // a_lds, rs_lds, xs ready

    // attn write, coalesced via LDS restage
    {
      int idx = tid;
#pragma unroll
      for (int rep = 0; rep < 3; ++rep) {
        if (idx < NSL * 64) {
          int k = idx >> 6, r = idx & 63;
          attn_out[((size_t)(b * NSL + k)) * NN + ch * 512 + T * 64 + r] = a_lds[r][k];
        }
        idx += 256;
      }
    }
    // phase C: acc[k] += sum_r a[r][k] * rstd_r * x[r][j]
    if (tid < DIM) {
      for (int r = 0; r < 64; ++r) {
        float t1 = rs_lds[r] * xs[r][tid];
        float4 a0 = *(const float4*)&a_lds[r][0];
        float4 a1 = *(const float4*)&a_lds[r][4];
        float4 a2 = *(const float4*)&a_lds[r][8];
        acc[0]  = fmaf(a0.x, t1, acc[0]);
        acc[1]  = fmaf(a0.y, t1, acc[1]);
        acc[2]  = fmaf(a0.z, t1, acc[2]);
        acc[3]  = fmaf(a0.w, t1, acc[3]);
        acc[4]  = fmaf(a1.x, t1, acc[4]);
        acc[5]  = fmaf(a1.y, t1, acc[5]);
        acc[6]  = fmaf(a1.z, t1, acc[6]);
        acc[7]  = fmaf(a1.w, t1, acc[7]);
        acc[8]  = fmaf(a2.x, t1, acc[8]);
        acc[9]  = fmaf(a2.y, t1, acc[9]);
        acc[10] = fmaf(a2.z, t1, acc[10]);
      }
    }
  }

  if (tid < DIM) {
#pragma unroll
    for (int k = 0; k < NSL; ++k)
      P1p[(((size_t)b * NCH + ch) * NSL + k) * DIM + tid] = acc[k];
  }
#pragma unroll
  for (int k = 0; k < NSL; ++k) { sS[k] = wred(sS[k]); sM[k] = wred(sM[k]); }
  if (lane == 0) {
#pragma unroll
    for (int k = 0; k < NSL; ++k) { redS[wave][k] = sS[k]; redM[wave][k] = sM[k]; }
  }
  __syncthreads();
  if (tid < NSL) {
    S_p[((size_t)b * NCH + ch) * NSL + tid]  = redS[0][tid] + redS[1][tid] + redS[2][tid] + redS[3][tid];
    m1_p[((size_t)b * NCH + ch) * NSL + tid] = redM[0][tid] + redM[1][tid] + redM[2][tid] + redM[3][tid];
  }
}

// ---------------------------------------------------------------- updates + GRU + LN + MLP + residual
__global__ __launch_bounds__(192) void k_gru(
    const float* __restrict__ P1p, const float* __restrict__ m1_p, const float* __restrict__ S_p,
    const float* __restrict__ xw, const float* __restrict__ xb,
    const float* __restrict__ Wv, const float* __restrict__ bv,
    const float* __restrict__ slots_in,
    const float* __restrict__ Wih, const float* __restrict__ Whh,
    const float* __restrict__ bih, const float* __restrict__ bhh,
    const float* __restrict__ lnw, const float* __restrict__ lnb,
    const float* __restrict__ W1, const float* __restrict__ b1,
    const float* __restrict__ W2, const float* __restrict__ b2,
    float* __restrict__ slots_ws, float* __restrict__ slots_out) {
  const int b = blockIdx.x, kg = blockIdx.y, tid = threadIdx.x;
  const int k0 = kg * 6, kcnt = kg ? 5 : 6;
  __shared__ __align__(16) float u[6][DIM];
  __shared__ __align__(16) float hp[6][DIM];
  __shared__ __align__(16) float h[6][DIM];
  __shared__ __align__(16) float hid[6][HIDN];

  const int j = tid;
  const float wj = xw[j], bj = xb[j];
#pragma unroll
  for (int kk = 0; kk < 6; ++kk) {
    if (kk < kcnt) {
      int kidx = b * NSL + k0 + kk;
      float p = 0.f, S = 0.f, M = 0.f;
#pragma unroll
      for (int ch = 0; ch < NCH; ++ch) {
        p += P1p[(((size_t)b * NCH + ch) * NSL + k0 + kk) * DIM + j];
        S += S_p[((size_t)b * NCH + ch) * NSL + k0 + kk];
        M += m1_p[((size_t)b * NCH + ch) * NSL + k0 + kk];
      }
      float inv = 1.0f / S;
      u[kk][j]  = wj * (p - M) * inv + bj;
      hp[kk][j] = slots_in[(size_t)kidx * DIM + j];
    } else { u[kk][j] = 0.f; hp[kk][j] = 0.f; }
  }
  __syncthreads();

  // updates = xa @ Wv + bv
  float upd[6];
  const float bvj = bv[j];
#pragma unroll
  for (int kk = 0; kk < 6; ++kk) upd[kk] = bvj;
  for (int d = 0; d < DIM; d += 4) {
    float w0 = Wv[(d + 0) * DIM + j], w1 = Wv[(d + 1) * DIM + j];
    float w2 = Wv[(d + 2) * DIM + j], w3 = Wv[(d + 3) * DIM + j];
#pragma unroll
    for (int kk = 0; kk < 6; ++kk) {
      float4 x4 = *(const float4*)&u[kk][d];
      upd[kk] = fmaf(x4.w, w3, fmaf(x4.z, w2, fmaf(x4.y, w1, fmaf(x4.x, w0, upd[kk]))));
    }
  }
  __syncthreads();
#pragma unroll
  for (int kk = 0; kk < 6; ++kk) u[kk][j] = upd[kk];
  __syncthreads();

  // GRU
  float xr[6], xz[6], xn[6], hr[6], hz[6], hn[6];
  {
    float br_ = bih[j], bz_ = bih[DIM + j], bn_ = bih[2 * DIM + j];
    float cr_ = bhh[j], cz_ = bhh[DIM + j], cn_ = bhh[2 * DIM + j];
#pragma unroll
    for (int kk = 0; kk < 6; ++kk) { xr[kk] = br_; xz[kk] = bz_; xn[kk] = bn_; hr[kk] = cr_; hz[kk] = cz_; hn[kk] = cn_; }
  }
  const float* wr = Wih + (size_t)j * DIM;
  const float* wz = Wih + (size_t)(DIM + j) * DIM;
  const float* wn = Wih + (size_t)(2 * DIM + j) * DIM;
  const float* vr = Whh + (size_t)j * DIM;
  const float* vz = Whh + (size_t)(DIM + j) * DIM;
  const float* vn = Whh + (size_t)(2 * DIM + j) * DIM;

  for (int d = 0; d < DIM; d += 4) {
    float4 ar  = *(const float4*)(wr + d);
    float4 az  = *(const float4*)(wz + d);
    float4 an  = *(const float4*)(wn + d);
    float4 br4 = *(const float4*)(vr + d);
    float4 bz4 = *(const float4*)(vz + d);
    float4 bn4 = *(const float4*)(vn + d);
#pragma unroll
    for (int kk = 0; kk < 6; ++kk) {
      float4 u4 = *(const float4*)&u[kk][d];
      float4 p4 = *(const float4*)&hp[kk][d];
      xr[kk] = fmaf(u4.w, ar.w, fmaf(u4.z, ar.z, fmaf(u4.y, ar.y, fmaf(u4.x, ar.x, xr[kk]))));
      xz[kk] = fmaf(u4.w, az.w, fmaf(u4.z, az.z, fmaf(u4.y, az.y, fmaf(u4.x, az.x, xz[kk]))));
      xn[kk] = fmaf(u4.w, an.w, fmaf(u4.z, an.z, fmaf(u4.y, an.y, fmaf(u4.x, an.x, xn[kk]))));
      hr[kk] = fmaf(p4.w, br4.w, fmaf(p4.z, br4.z, fmaf(p4.y, br4.y, fmaf(p4.x, br4.x, hr[kk]))));
      hz[kk] = fmaf(p4.w, bz4.w, fmaf(p4.z, bz4.z, fmaf(p4.y, bz4.y, fmaf(p4.x, bz4.x, hz[kk]))));
      hn[kk] = fmaf(p4.w, bn4.w, fmaf(p4.z, bn4.z, fmaf(p4.y, bn4.y, fmaf(p4.x, bn4.x, hn[kk]))));
    }
  }

#pragma unroll
  for (int kk = 0; kk < 6; ++kk) {
    if (kk < kcnt) {
      float r = 1.f / (1.f + __expf(-(xr[kk] + hr[kk])));
      float z = 1.f / (1.f + __expf(-(xz[kk] + hz[kk])));
      float n = tanhf(xn[kk] + r * hn[kk]);
      h[kk][j] = (1.f - z) * n + z * hp[kk][j];
    }
  }
  __syncthreads();

  const int wave = tid >> 6, lane = tid & 63;
  for (int kk = wave; kk < kcnt; kk += 3) {
    float a = h[kk][lane], c = h[kk][lane + 64], e = h[kk][lane + 128];
    float s = wred(a + c + e), ss = wred(a * a + c * c + e * e);
    float mu = s * (1.0f / DIM), var = ss * (1.0f / DIM) - mu * mu;
    float rstd = rsqrtf(var + LN_EPS);
    u[kk][lane]       = (a - mu) * rstd * lnw[lane]       + lnb[lane];
    u[kk][lane + 64]  = (c - mu) * rstd * lnw[lane + 64]  + lnb[lane + 64];
    u[kk][lane + 128] = (e - mu) * rstd * lnw[lane + 128] + lnb[lane + 128];
  }
  __syncthreads();

  for (int t = tid; t < kcnt * HIDN; t += 192) {
    int kk = t >> 7, c = t & (HIDN - 1);
    float acc = b1[c];
    for (int d = 0; d < DIM; d += 4) {
      float4 m4 = *(const float4*)&u[kk][d];
      acc = fmaf(m4.x, W1[(d + 0) * HIDN + c],
            fmaf(m4.y, W1[(d + 1) * HIDN + c],
            fmaf(m4.z, W1[(d + 2) * HIDN + c],
            fmaf(m4.w, W1[(d + 3) * HIDN + c], acc))));
    }
    hid[kk][c] = fmaxf(acc, 0.f);
  }
  __syncthreads();

  for (int kk = 0; kk < kcnt; ++kk) {
    float acc = b2[tid];
    for (int c = 0; c < HIDN; c += 4) {
      float4 h4 = *(const float4*)&hid[kk][c];
      acc = fmaf(h4.x, W2[(c + 0) * DIM + tid],
            fmaf(h4.y, W2[(c + 1) * DIM + tid],
            fmaf(h4.z, W2[(c + 2) * DIM + tid],
            fmaf(h4.w, W2[(c + 3) * DIM + tid], acc))));
    }
    float outv = h[kk][tid] + acc;
    size_t gi = (size_t)(b * NSL + k0 + kk) * DIM + tid;
    slots_ws[gi] = outv;
    slots_out[gi] = outv;
  }
}

// ---------------------------------------------------------------- launch
extern "C" void kernel_launch(void* const* d_in, const int* in_sizes, int n_in,
                              void* d_out, int out_size, void* d_ws, size_t ws_size,
                              hipStream_t stream) {
  const float* inputs      = (const float*)d_in[0];
  const float* noise       = (const float*)d_in[1];
  const float* slots_mu    = (const float*)d_in[2];
  const float* slots_sigma = (const float*)d_in[3];
  const float* ln_in_w     = (const float*)d_in[4];
  const float* ln_in_b     = (const float*)d_in[5];
  const float* ln_slots_w  = (const float*)d_in[6];
  const float* ln_slots_b  = (const float*)d_in[7];
  const float* ln_mlp_w    = (const float*)d_in[8];
  const float* ln_mlp_b    = (const float*)d_in[9];
  const float* Wq  = (const float*)d_in[10];
  const float* bq  = (const float*)d_in[11];
  const float* Wk  = (const float*)d_in[12];
  const float* bk  = (const float*)d_in[13];
  const float* Wv  = (const float*)d_in[14];
  const float* bv  = (const float*)d_in[15];
  const float* Wih = (const float*)d_in[16];
  const float* Whh = (const float*)d_in[17];
  const float* bih = (const float*)d_in[18];
  const float* bhh = (const float*)d_in[19];
  const float* W1  = (const float*)d_in[20];
  const float* b1  = (const float*)d_in[21];
  const float* W2  = (const float*)d_in[22];
  const float* b2  = (const float*)d_in[23];

  float* out = (float*)d_out;
  float* slots_out = out;                      // [64,11,192] fp32
  float* attn_out  = out + NB * NSL * DIM;     // [64,11,4096] fp32

  // workspace (~5.2 MiB):
  char* w = (char*)d_ws;
  float* slots = (float*)w;                    //  540672 B
  float* qt    = (float*)(w + 540672);         //  540672 B
  float* t0g   = (float*)(w + 1081344);        //    2816 B
  float* cpg   = (float*)(w + 1084160);        //    2816 B
  float* P1p   = (float*)(w + 1086976);        // 4325376 B  [64][8][11][192]
  float* S_p   = (float*)(w + 5412352);        //   22528 B  [64][8][11]
  float* m1_p  = (float*)(w + 5434880);        //   22528 B

  k_init_slots<<<(NB * NSL * DIM + 255) / 256, 256, 0, stream>>>(noise, slots_mu, slots_sigma, slots);

  for (int it = 0; it < 3; ++it) {
    k_prep<<<NB, 192, 0, stream>>>(slots, ln_slots_w, ln_slots_b, Wq, bq, Wk, bk,
                                   ln_in_w, ln_in_b, qt, t0g, cpg);
    k_iter<<<dim3(NB, NCH), 256, 0, stream>>>(inputs, qt, t0g, cpg, attn_out, P1p, S_p, m1_p);
    k_gru<<<dim3(NB, 2), 192, 0, stream>>>(P1p, m1_p, S_p, ln_in_w, ln_in_b, Wv, bv, slots,
                                           Wih, Whh, bih, bhh, ln_mlp_w, ln_mlp_b,
                                           W1, b1, W2, b2, slots, slots_out);
  }
}

// Round 5
// 1093.006 us; speedup vs baseline: 1.7429x; 1.7429x over previous
//
#include <hip/hip_runtime.h>
#include <hip/hip_bf16.h>
#include <cstdint>
#include <cstddef>

#define DIM 192
#define NSL 11
#define NB 64
#define NN 4096
#define HIDN 128
#define NCHP 16        // chunks per batch in k_iter (256 rows each)
#define LN_EPS 1e-5f
#define EPS_A 1e-8f
#define SCALE_Q 0.07216878364870323f  // 192^-0.5

// ---------------------------------------------------------------- utilities
__device__ __forceinline__ float wred(float v) {
#pragma unroll
  for (int m = 32; m; m >>= 1) v += __shfl_xor(v, m, 64);
  return v;
}

// ---------------------------------------------------------------- per-iter prep: (optional slots init) + LN(slots) -> q -> folded query
// qt[k][e] = SCALE * ln_in_w[e] * (q[k] @ Wk^T)[e];  t0[k] = sum_e qt;  cp[k] = SCALE*(q.bk + sum_e ln_in_b[e]*qk[k][e])
__global__ __launch_bounds__(192) void k_prep(
    const float* __restrict__ slots_g, const float* __restrict__ lnw, const float* __restrict__ lnb,
    const float* __restrict__ Wq, const float* __restrict__ bq,
    const float* __restrict__ Wk, const float* __restrict__ bk,
    const float* __restrict__ xw, const float* __restrict__ xb,
    const float* __restrict__ noise, const float* __restrict__ mu0, const float* __restrict__ sig,
    float* __restrict__ slots_ws, int do_init,
    float* __restrict__ qt, float* __restrict__ t0g, float* __restrict__ cpg) {
  const int b = blockIdx.x, tid = threadIdx.x, wave = tid >> 6, lane = tid & 63;
  __shared__ __align__(16) float sl[NSL][DIM];
  __shared__ __align__(16) float sn[NSL][DIM];
  __shared__ __align__(16) float qb[NSL][DIM];
  __shared__ float red[3][NSL][2];

  if (do_init) {
    const float m = mu0[tid], sg = sig[tid];
#pragma unroll
    for (int k = 0; k < NSL; ++k) {
      float v = m + sg * noise[(size_t)(b * NSL + k) * DIM + tid];
      sl[k][tid] = v;
      slots_ws[(size_t)(b * NSL + k) * DIM + tid] = v;
    }
  } else {
#pragma unroll
    for (int k = 0; k < NSL; ++k)
      sl[k][tid] = slots_g[(size_t)(b * NSL + k) * DIM + tid];
  }
  __syncthreads();

  for (int k = wave; k < NSL; k += 3) {
    float a = sl[k][lane], c = sl[k][lane + 64], e = sl[k][lane + 128];
    float s = wred(a + c + e), ss = wred(a * a + c * c + e * e);
    float mu = s * (1.0f / DIM), var = ss * (1.0f / DIM) - mu * mu;
    float rstd = rsqrtf(var + LN_EPS);
    sn[k][lane]       = (a - mu) * rstd * lnw[lane]       + lnb[lane];
    sn[k][lane + 64]  = (c - mu) * rstd * lnw[lane + 64]  + lnb[lane + 64];
    sn[k][lane + 128] = (e - mu) * rstd * lnw[lane + 128] + lnb[lane + 128];
  }
  __syncthreads();

  const int j = tid;
  float acc[NSL];
  const float bj = bq[j];
#pragma unroll
  for (int k = 0; k < NSL; ++k) acc[k] = bj;
  for (int d = 0; d < DIM; d += 4) {
    float w0 = Wq[(d + 0) * DIM + j], w1 = Wq[(d + 1) * DIM + j];
    float w2 = Wq[(d + 2) * DIM + j], w3 = Wq[(d + 3) * DIM + j];
#pragma unroll
    for (int k = 0; k < NSL; ++k) {
      float4 s4 = *(const float4*)&sn[k][d];
      acc[k] = fmaf(s4.w, w3, fmaf(s4.z, w2, fmaf(s4.y, w1, fmaf(s4.x, w0, acc[k]))));
    }
  }
#pragma unroll
  for (int k = 0; k < NSL; ++k) qb[k][j] = acc[k];
  __syncthreads();

  float qk[NSL];
#pragma unroll
  for (int k = 0; k < NSL; ++k) qk[k] = 0.f;
  const float* wkr = Wk + (size_t)j * DIM;
  for (int d = 0; d < DIM; d += 4) {
    float4 w4 = *(const float4*)(wkr + d);
#pragma unroll
    for (int k = 0; k < NSL; ++k) {
      float4 q4 = *(const float4*)&qb[k][d];
      qk[k] = fmaf(w4.w, q4.w, fmaf(w4.z, q4.z, fmaf(w4.y, q4.y, fmaf(w4.x, q4.x, qk[k]))));
    }
  }
  const float wj = xw[j], bxj = xb[j], bkj = bk[j];
#pragma unroll
  for (int k = 0; k < NSL; ++k) {
    float qtv = SCALE_Q * wj * qk[k];
    qt[((size_t)b * NSL + k) * DIM + j] = qtv;
    float r1 = wred(qtv);
    float r2 = wred(SCALE_Q * (bxj * qk[k] + qb[k][j] * bkj));
    if (lane == 0) { red[wave][k][0] = r1; red[wave][k][1] = r2; }
  }
  __syncthreads();
  if (tid < NSL) {
    t0g[b * NSL + tid] = red[0][tid][0] + red[1][tid][0] + red[2][tid][0];
    cpg[b * NSL + tid] = red[0][tid][1] + red[1][tid][1] + red[2][tid][1];
  }
}

// ---------------------------------------------------------------- fused iteration kernel
// grid (64, 16) x 256 threads. Block handles 256 rows = 4 tiles of 64.
// dots: thread (g=t>>4, widx=t&15) owns rows 4g..4g+3, cols {widx,widx+16,widx+32}*4.
// phase C: wave wv owns rows r= 4i+wv; lane owns cols {l, l+64, l+128}.
__global__ __launch_bounds__(256) void k_iter(
    const float* __restrict__ x, const float* __restrict__ qt,
    const float* __restrict__ t0g, const float* __restrict__ cpg,
    float* __restrict__ attn_out, float* __restrict__ P1p,
    float* __restrict__ S_p, float* __restrict__ m1_p) {
  __shared__ float xs_raw[64 * 196];          // 64 rows, stride 196 floats (49 f4), XOR-swizzled cols
  __shared__ float qs[NSL * DIM];
  __shared__ __align__(16) float a_lds[64][12];
  __shared__ float rs_lds[64];
  __shared__ float t0s[NSL], cps[NSL];
  __shared__ float redS[4][NSL], redM[4][NSL];
  float4* xs4 = (float4*)xs_raw;

  const int b = blockIdx.x, ch = blockIdx.y, tid = threadIdx.x;
  const int lane = tid & 63, wv = tid >> 6;
  const int widx = tid & 15, g = tid >> 4;

  for (int t = tid; t < NSL * DIM; t += 256) qs[t] = qt[(size_t)b * NSL * DIM + t];
  if (tid < NSL) { t0s[tid] = t0g[b * NSL + tid]; cps[tid] = cpg[b * NSL + tid]; }

  const float* xbase = x + ((size_t)b * NN + ch * 256) * DIM;
  float4 xv[12];
  {
    const float4* gp = (const float4*)xbase;
#pragma unroll
    for (int i = 0; i < 12; ++i) xv[i] = gp[i * 256 + tid];
  }

  float acc[3][NSL];
  float sS[NSL], sM[NSL];
#pragma unroll
  for (int k = 0; k < NSL; ++k) {
    acc[0][k] = 0.f; acc[1][k] = 0.f; acc[2][k] = 0.f;
    sS[k] = 0.f; sM[k] = 0.f;
  }

#pragma unroll 1
  for (int T = 0; T < 4; ++T) {
    __syncthreads();                       // xs free (phase C of prev tile done)
#pragma unroll
    for (int i = 0; i < 12; ++i) {
      int f = i * 256 + tid;
      int row = f / 48, c4 = f % 48;
      xs4[row * 49 + (c4 ^ (row & 7))] = xv[i];
    }
    if (T < 3) {
      const float4* gp = (const float4*)(xbase + (size_t)(T + 1) * 64 * DIM);
#pragma unroll
      for (int i = 0; i < 12; ++i) xv[i] = gp[i * 256 + tid];
    }
    __syncthreads();                       // xs ready

    // ---- dots + LN stats
    float dot[4][NSL], st_s[4], st_ss[4];
#pragma unroll
    for (int rr = 0; rr < 4; ++rr) {
      st_s[rr] = 0.f; st_ss[rr] = 0.f;
#pragma unroll
      for (int k = 0; k < NSL; ++k) dot[rr][k] = 0.f;
    }
#pragma unroll
    for (int w = 0; w < 3; ++w) {
      const int c4 = widx + 16 * w;
      float4 xr[4];
#pragma unroll
      for (int rr = 0; rr < 4; ++rr) {
        const int r = 4 * g + rr;
        xr[rr] = xs4[r * 49 + (c4 ^ (r & 7))];
        st_s[rr] += (xr[rr].x + xr[rr].y) + (xr[rr].z + xr[rr].w);
        st_ss[rr] = fmaf(xr[rr].x, xr[rr].x, fmaf(xr[rr].y, xr[rr].y,
                    fmaf(xr[rr].z, xr[rr].z, fmaf(xr[rr].w, xr[rr].w, st_ss[rr]))));
      }
#pragma unroll
      for (int k = 0; k < NSL; ++k) {
        float4 qv = *(const float4*)&qs[k * DIM + 4 * c4];
#pragma unroll
        for (int rr = 0; rr < 4; ++rr)
          dot[rr][k] = fmaf(xr[rr].w, qv.w, fmaf(xr[rr].z, qv.z,
                       fmaf(xr[rr].y, qv.y, fmaf(xr[rr].x, qv.x, dot[rr][k]))));
      }
    }
    // ---- reduce across the 16 widx lanes
#pragma unroll
    for (int m = 1; m <= 8; m <<= 1) {
#pragma unroll
      for (int rr = 0; rr < 4; ++rr) {
        st_s[rr] += __shfl_xor(st_s[rr], m, 64);
        st_ss[rr] += __shfl_xor(st_ss[rr], m, 64);
#pragma unroll
        for (int k = 0; k < NSL; ++k) dot[rr][k] += __shfl_xor(dot[rr][k], m, 64);
      }
    }
    // ---- softmax on widx==0 lanes (one per 4 rows)
    if (widx == 0) {
#pragma unroll
      for (int rr = 0; rr < 4; ++rr) {
        const int r = 4 * g + rr;
        float mu = st_s[rr] * (1.0f / DIM);
        float var = st_ss[rr] * (1.0f / DIM) - mu * mu;
        float rstd = rsqrtf(var + LN_EPS);
        float murstd = mu * rstd;
        float dv[NSL];
#pragma unroll
        for (int k = 0; k < NSL; ++k) dv[k] = fmaf(rstd, dot[rr][k], fmaf(-murstd, t0s[k], cps[k]));
        float mx = dv[0];
#pragma unroll
        for (int k = 1; k < NSL; ++k) mx = fmaxf(mx, dv[k]);
        float es[NSL], sum = 0.f;
#pragma unroll
        for (int k = 0; k < NSL; ++k) { es[k] = __expf(dv[k] - mx); sum += es[k]; }
        float inv = 1.0f / sum;
#pragma unroll
        for (int k = 0; k < NSL; ++k) {
          float a = fmaf(es[k], inv, EPS_A);
          a_lds[r][k] = a;
          sS[k] += a;
          sM[k] = fmaf(a, murstd, sM[k]);
        }
        rs_lds[r] = rstd;
      }
    }
    __syncthreads();                       // a_lds, rs_lds ready; xs stable

    // ---- attn write (coalesced 64-float runs)
    {
      int idx = tid;
#pragma unroll
      for (int rep = 0; rep < 3; ++rep) {
        if (idx < NSL * 64) {
          int k = idx >> 6, r = idx & 63;
          attn_out[((size_t)(b * NSL + k)) * NN + ch * 256 + T * 64 + r] = a_lds[r][k];
        }
        idx += 256;
      }
    }
    // ---- phase C: acc[j][k] += a[r][k] * rstd_r * x[r][col]
#pragma unroll 4
    for (int i = 0; i < 16; ++i) {
      const int r = 4 * i + wv;
      float rst = rs_lds[r];
      float4 a0 = *(const float4*)&a_lds[r][0];
      float4 a1 = *(const float4*)&a_lds[r][4];
      float4 a2 = *(const float4*)&a_lds[r][8];
#pragma unroll
      for (int j = 0; j < 3; ++j) {
        const int col = lane + 64 * j;
        const int c4 = col >> 2;
        float xval = xs_raw[r * 196 + (((c4 ^ (r & 7)) << 2) | (col & 3))];
        float t1 = rst * xval;
        acc[j][0]  = fmaf(a0.x, t1, acc[j][0]);
        acc[j][1]  = fmaf(a0.y, t1, acc[j][1]);
        acc[j][2]  = fmaf(a0.z, t1, acc[j][2]);
        acc[j][3]  = fmaf(a0.w, t1, acc[j][3]);
        acc[j][4]  = fmaf(a1.x, t1, acc[j][4]);
        acc[j][5]  = fmaf(a1.y, t1, acc[j][5]);
        acc[j][6]  = fmaf(a1.z, t1, acc[j][6]);
        acc[j][7]  = fmaf(a1.w, t1, acc[j][7]);
        acc[j][8]  = fmaf(a2.x, t1, acc[j][8]);
        acc[j][9]  = fmaf(a2.y, t1, acc[j][9]);
        acc[j][10] = fmaf(a2.z, t1, acc[j][10]);
      }
    }
  }

  // ---- reduce acc across waves (alias xs_raw) and write P1 partials
  __syncthreads();
  float* accbuf = xs_raw;                  // 256*33 = 8448 floats < 12544
#pragma unroll
  for (int j = 0; j < 3; ++j)
#pragma unroll
    for (int k = 0; k < NSL; ++k)
      accbuf[tid * 33 + j * 11 + k] = acc[j][k];
  __syncthreads();
  if (tid < DIM) {
    const int l = tid & 63, j = tid >> 6;
#pragma unroll
    for (int k = 0; k < NSL; ++k) {
      float v = accbuf[(l) * 33 + j * 11 + k] + accbuf[(64 + l) * 33 + j * 11 + k]
              + accbuf[(128 + l) * 33 + j * 11 + k] + accbuf[(192 + l) * 33 + j * 11 + k];
      P1p[(((size_t)b * NCHP + ch) * NSL + k) * DIM + tid] = v;
    }
  }
#pragma unroll
  for (int k = 0; k < NSL; ++k) { sS[k] = wred(sS[k]); sM[k] = wred(sM[k]); }
  if (lane == 0) {
#pragma unroll
    for (int k = 0; k < NSL; ++k) { redS[wv][k] = sS[k]; redM[wv][k] = sM[k]; }
  }
  __syncthreads();
  if (tid < NSL) {
    S_p[((size_t)b * NCHP + ch) * NSL + tid]  = redS[0][tid] + redS[1][tid] + redS[2][tid] + redS[3][tid];
    m1_p[((size_t)b * NCHP + ch) * NSL + tid] = redM[0][tid] + redM[1][tid] + redM[2][tid] + redM[3][tid];
  }
}

// ---------------------------------------------------------------- updates + GRU + LN + MLP + residual
__global__ __launch_bounds__(192) void k_gru(
    const float* __restrict__ P1p, const float* __restrict__ m1_p, const float* __restrict__ S_p,
    const float* __restrict__ xw, const float* __restrict__ xb,
    const float* __restrict__ Wv, const float* __restrict__ bv,
    const float* __restrict__ slots_in,
    const float* __restrict__ Wih, const float* __restrict__ Whh,
    const float* __restrict__ bih, const float* __restrict__ bhh,
    const float* __restrict__ lnw, const float* __restrict__ lnb,
    const float* __restrict__ W1, const float* __restrict__ b1,
    const float* __restrict__ W2, const float* __restrict__ b2,
    float* __restrict__ slots_ws, float* __restrict__ slots_out) {
  const int b = blockIdx.x, kg = blockIdx.y, tid = threadIdx.x;
  const int k0 = kg * 6, kcnt = kg ? 5 : 6;
  __shared__ __align__(16) float u[6][DIM];
  __shared__ __align__(16) float hp[6][DIM];
  __shared__ __align__(16) float h[6][DIM];
  __shared__ __align__(16) float hid[6][HIDN];

  const int j = tid;
  const float wj = xw[j], bj = xb[j];
#pragma unroll
  for (int kk = 0; kk < 6; ++kk) {
    if (kk < kcnt) {
      int kidx = b * NSL + k0 + kk;
      float p = 0.f, S = 0.f, M = 0.f;
#pragma unroll
      for (int ch = 0; ch < NCHP; ++ch) {
        p += P1p[(((size_t)b * NCHP + ch) * NSL + k0 + kk) * DIM + j];
        S += S_p[((size_t)b * NCHP + ch) * NSL + k0 + kk];
        M += m1_p[((size_t)b * NCHP + ch) * NSL + k0 + kk];
      }
      float inv = 1.0f / S;
      u[kk][j]  = wj * (p - M) * inv + bj;
      hp[kk][j] = slots_in[(size_t)kidx * DIM + j];
    } else { u[kk][j] = 0.f; hp[kk][j] = 0.f; }
  }
  __syncthreads();

  // updates = xa @ Wv + bv
  float upd[6];
  const float bvj = bv[j];
#pragma unroll
  for (int kk = 0; kk < 6; ++kk) upd[kk] = bvj;
  for (int d = 0; d < DIM; d += 4) {
    float w0 = Wv[(d + 0) * DIM + j], w1 = Wv[(d + 1) * DIM + j];
    float w2 = Wv[(d + 2) * DIM + j], w3 = Wv[(d + 3) * DIM + j];
#pragma unroll
    for (int kk = 0; kk < 6; ++kk) {
      float4 x4 = *(const float4*)&u[kk][d];
      upd[kk] = fmaf(x4.w, w3, fmaf(x4.z, w2, fmaf(x4.y, w1, fmaf(x4.x, w0, upd[kk]))));
    }
  }
  __syncthreads();
#pragma unroll
  for (int kk = 0; kk < 6; ++kk) u[kk][j] = upd[kk];
  __syncthreads();

  // GRU
  float xr[6], xz[6], xn[6], hr[6], hz[6], hn[6];
  {
    float br_ = bih[j], bz_ = bih[DIM + j], bn_ = bih[2 * DIM + j];
    float cr_ = bhh[j], cz_ = bhh[DIM + j], cn_ = bhh[2 * DIM + j];
#pragma unroll
    for (int kk = 0; kk < 6; ++kk) { xr[kk] = br_; xz[kk] = bz_; xn[kk] = bn_; hr[kk] = cr_; hz[kk] = cz_; hn[kk] = cn_; }
  }
  const float* wr = Wih + (size_t)j * DIM;
  const float* wz = Wih + (size_t)(DIM + j) * DIM;
  const float* wn = Wih + (size_t)(2 * DIM + j) * DIM;
  const float* vr = Whh + (size_t)j * DIM;
  const float* vz = Whh + (size_t)(DIM + j) * DIM;
  const float* vn = Whh + (size_t)(2 * DIM + j) * DIM;

  for (int d = 0; d < DIM; d += 4) {
    float4 ar  = *(const float4*)(wr + d);
    float4 az  = *(const float4*)(wz + d);
    float4 an  = *(const float4*)(wn + d);
    float4 br4 = *(const float4*)(vr + d);
    float4 bz4 = *(const float4*)(vz + d);
    float4 bn4 = *(const float4*)(vn + d);
#pragma unroll
    for (int kk = 0; kk < 6; ++kk) {
      float4 u4 = *(const float4*)&u[kk][d];
      float4 p4 = *(const float4*)&hp[kk][d];
      xr[kk] = fmaf(u4.w, ar.w, fmaf(u4.z, ar.z, fmaf(u4.y, ar.y, fmaf(u4.x, ar.x, xr[kk]))));
      xz[kk] = fmaf(u4.w, az.w, fmaf(u4.z, az.z, fmaf(u4.y, az.y, fmaf(u4.x, az.x, xz[kk]))));
      xn[kk] = fmaf(u4.w, an.w, fmaf(u4.z, an.z, fmaf(u4.y, an.y, fmaf(u4.x, an.x, xn[kk]))));
      hr[kk] = fmaf(p4.w, br4.w, fmaf(p4.z, br4.z, fmaf(p4.y, br4.y, fmaf(p4.x, br4.x, hr[kk]))));
      hz[kk] = fmaf(p4.w, bz4.w, fmaf(p4.z, bz4.z, fmaf(p4.y, bz4.y, fmaf(p4.x, bz4.x, hz[kk]))));
      hn[kk] = fmaf(p4.w, bn4.w, fmaf(p4.z, bn4.z, fmaf(p4.y, bn4.y, fmaf(p4.x, bn4.x, hn[kk]))));
    }
  }

#pragma unroll
  for (int kk = 0; kk < 6; ++kk) {
    if (kk < kcnt) {
      float r = 1.f / (1.f + __expf(-(xr[kk] + hr[kk])));
      float z = 1.f / (1.f + __expf(-(xz[kk] + hz[kk])));
      float n = tanhf(xn[kk] + r * hn[kk]);
      h[kk][j] = (1.f - z) * n + z * hp[kk][j];
    }
  }
  __syncthreads();

  const int wave = tid >> 6, lane = tid & 63;
  for (int kk = wave; kk < kcnt; kk += 3) {
    float a = h[kk][lane], c = h[kk][lane + 64], e = h[kk][lane + 128];
    float s = wred(a + c + e), ss = wred(a * a + c * c + e * e);
    float mu = s * (1.0f / DIM), var = ss * (1.0f / DIM) - mu * mu;
    float rstd = rsqrtf(var + LN_EPS);
    u[kk][lane]       = (a - mu) * rstd * lnw[lane]       + lnb[lane];
    u[kk][lane + 64]  = (c - mu) * rstd * lnw[lane + 64]  + lnb[lane + 64];
    u[kk][lane + 128] = (e - mu) * rstd * lnw[lane + 128] + lnb[lane + 128];
  }
  __syncthreads();

  for (int t = tid; t < kcnt * HIDN; t += 192) {
    int kk = t >> 7, c = t & (HIDN - 1);
    float acc = b1[c];
    for (int d = 0; d < DIM; d += 4) {
      float4 m4 = *(const float4*)&u[kk][d];
      acc = fmaf(m4.x, W1[(d + 0) * HIDN + c],
            fmaf(m4.y, W1[(d + 1) * HIDN + c],
            fmaf(m4.z, W1[(d + 2) * HIDN + c],
            fmaf(m4.w, W1[(d + 3) * HIDN + c], acc))));
    }
    hid[kk][c] = fmaxf(acc, 0.f);
  }
  __syncthreads();

  for (int kk = 0; kk < kcnt; ++kk) {
    float acc = b2[tid];
    for (int c = 0; c < HIDN; c += 4) {
      float4 h4 = *(const float4*)&hid[kk][c];
      acc = fmaf(h4.x, W2[(c + 0) * DIM + tid],
            fmaf(h4.y, W2[(c + 1) * DIM + tid],
            fmaf(h4.z, W2[(c + 2) * DIM + tid],
            fmaf(h4.w, W2[(c + 3) * DIM + tid], acc))));
    }
    float outv = h[kk][tid] + acc;
    size_t gi = (size_t)(b * NSL + k0 + kk) * DIM + tid;
    slots_ws[gi] = outv;
    slots_out[gi] = outv;
  }
}

// ---------------------------------------------------------------- launch
extern "C" void kernel_launch(void* const* d_in, const int* in_sizes, int n_in,
                              void* d_out, int out_size, void* d_ws, size_t ws_size,
                              hipStream_t stream) {
  const float* inputs      = (const float*)d_in[0];
  const float* noise       = (const float*)d_in[1];
  const float* slots_mu    = (const float*)d_in[2];
  const float* slots_sigma = (const float*)d_in[3];
  const float* ln_in_w     = (const float*)d_in[4];
  const float* ln_in_b     = (const float*)d_in[5];
  const float* ln_slots_w  = (const float*)d_in[6];
  const float* ln_slots_b  = (const float*)d_in[7];
  const float* ln_mlp_w    = (const float*)d_in[8];
  const float* ln_mlp_b    = (const float*)d_in[9];
  const float* Wq  = (const float*)d_in[10];
  const float* bq  = (const float*)d_in[11];
  const float* Wk  = (const float*)d_in[12];
  const float* bk  = (const float*)d_in[13];
  const float* Wv  = (const float*)d_in[14];
  const float* bv  = (const float*)d_in[15];
  const float* Wih = (const float*)d_in[16];
  const float* Whh = (const float*)d_in[17];
  const float* bih = (const float*)d_in[18];
  const float* bhh = (const float*)d_in[19];
  const float* W1  = (const float*)d_in[20];
  const float* b1  = (const float*)d_in[21];
  const float* W2  = (const float*)d_in[22];
  const float* b2  = (const float*)d_in[23];

  float* out = (float*)d_out;
  float* slots_out = out;                      // [64,11,192] fp32
  float* attn_out  = out + NB * NSL * DIM;     // [64,11,4096] fp32

  // workspace (~9.4 MiB):
  char* w = (char*)d_ws;
  float* slots = (float*)w;                    //  540672 B
  float* qt    = (float*)(w + 540672);         //  540672 B
  float* t0g   = (float*)(w + 1081344);        //    2816 B
  float* cpg   = (float*)(w + 1084160);        //    2816 B
  float* P1p   = (float*)(w + 1086976);        // 8650752 B  [64][16][11][192]
  float* S_p   = (float*)(w + 9737728);        //   45056 B  [64][16][11]
  float* m1_p  = (float*)(w + 9782784);        //   45056 B

  for (int it = 0; it < 3; ++it) {
    k_prep<<<NB, 192, 0, stream>>>(slots, ln_slots_w, ln_slots_b, Wq, bq, Wk, bk,
                                   ln_in_w, ln_in_b, noise, slots_mu, slots_sigma,
                                   slots, (it == 0) ? 1 : 0, qt, t0g, cpg);
    k_iter<<<dim3(NB, NCHP), 256, 0, stream>>>(inputs, qt, t0g, cpg, attn_out, P1p, S_p, m1_p);
    k_gru<<<dim3(NB, 2), 192, 0, stream>>>(P1p, m1_p, S_p, ln_in_w, ln_in_b, Wv, bv, slots,
                                           Wih, Whh, bih, bhh, ln_mlp_w, ln_mlp_b,
                                           W1, b1, W2, b2, slots, slots_out);
  }
}